// Round 5
// baseline (220.010 us; speedup 1.0000x reference)
//
#include <hip/hip_runtime.h>
#include <math.h>

// Problem constants (from reference):
//   N=32, C=1, H=512, W=1024 -> HW = 524288 per batch row
//   SAMPLE_NUM = 5000 pairs per row -> 160000 pairs total
//   SIGMA = 0.03, ALPHA = 1.0, EPS = 1e-6, LOSS_WEIGHT = 1.0
#define SAMPLE_NUM 5000
#define HWSZ (512 * 1024)
#define SIGMA_F 0.03f
#define EPS_F 1e-6f
#define BLOCK 256
#define K1_THREADS 512
#define ROW_BITS_PAD 5120            // per-row bitmap bits (5000 used)
#define BM_OFF_BYTES 8192            // bitmap at ws+8192; 32*640B = 20 KB

// R8b design notes (R8 bench was an infra failure — never ran; same design):
//  - R7 post-mortem: packed-2MB mask gathers nulled because EACH XCD's
//    private L2 refetches its own copy of every touched line (~1.25
//    requests/line/XCD -> zero reuse). Global-memory mask gathering is
//    unfixable by footprint shrinking; take mask out of the memory system.
//  - K1 (32 blocks, one per row): stream row mask coalesced, bit-pack to
//    64 KB LDS (R7-validated pack trick), evaluate all 5000 pair
//    validities via LDS lookups, __ballot -> 20 KB validity bitmap in ws.
//  - K2 never touches mask: 1 coalesced bitmap bit per pair + only the
//    mandatory ~137k valid-lane data-gather lines (~9 MB random HBM).
//  - Net: ~15 MB scattered cold mask lines -> 16 MB coalesced stream.

__device__ __forceinline__ unsigned pack16_bytes(uint4 v) {
  // 16 bool bytes -> 16 bits. ((u & 0x01010101)*0x01020408)>>24 puts the
  // 4 byte-LSBs at bits 0..3. Validated end-to-end in R7 (absmax=0).
  const unsigned n0 = ((v.x & 0x01010101u) * 0x01020408u) >> 24;
  const unsigned n1 = ((v.y & 0x01010101u) * 0x01020408u) >> 24;
  const unsigned n2 = ((v.z & 0x01010101u) * 0x01020408u) >> 24;
  const unsigned n3 = ((v.w & 0x01010101u) * 0x01020408u) >> 24;
  return (n0 & 0xFu) | ((n1 & 0xFu) << 4) | ((n2 & 0xFu) << 8) |
         ((n3 & 0xFu) << 12);
}

__device__ __forceinline__ unsigned lsb4_i32(uint4 v) {
  return (v.x & 1u) | ((v.y & 1u) << 1) | ((v.z & 1u) << 2) |
         ((v.w & 1u) << 3);
}

// Kernel 1: one block per batch row. Stream+pack row mask into LDS, then
// evaluate validity of the row's 5000 pairs; ballot -> bitmap in ws.
__global__ void __launch_bounds__(K1_THREADS)
mask_validity(const void* __restrict__ mask_raw,
              const int* __restrict__ idxA, const int* __restrict__ idxB,
              unsigned long long* __restrict__ bitmap) {
  extern __shared__ unsigned int sbm[];  // HWSZ/32 = 16384 words = 64 KB
  const int n = blockIdx.x;
  const int t = threadIdx.x;

  // Mask layout detection (thread-uniform; same scheme as prior rounds).
  const unsigned int* mw = (const unsigned int*)mask_raw;
  bool mask_is_i32 = true;
  #pragma unroll
  for (int w = 0; w < 32; ++w) {
    if (mw[w] > 1u) mask_is_i32 = false;
  }

  unsigned short* sbm16 = (unsigned short*)sbm;
  if (!mask_is_i32) {
    // Byte bools: row = 512 KB = 32768 uint4 chunks; chunk c -> bits
    // [16c,16c+16) -> ushort slot c. 4 independent loads/iter for MLP.
    const uint4* src =
        (const uint4*)((const unsigned char*)mask_raw + (size_t)n * HWSZ);
    #pragma unroll
    for (int it = 0; it < 16; ++it) {
      const int c0 = t + (it * 4 + 0) * K1_THREADS;
      const int c1 = t + (it * 4 + 1) * K1_THREADS;
      const int c2 = t + (it * 4 + 2) * K1_THREADS;
      const int c3 = t + (it * 4 + 3) * K1_THREADS;
      const uint4 v0 = src[c0];
      const uint4 v1 = src[c1];
      const uint4 v2 = src[c2];
      const uint4 v3 = src[c3];
      sbm16[c0] = (unsigned short)pack16_bytes(v0);
      sbm16[c1] = (unsigned short)pack16_bytes(v1);
      sbm16[c2] = (unsigned short)pack16_bytes(v2);
      sbm16[c3] = (unsigned short)pack16_bytes(v3);
    }
  } else {
    // int32 bools: row = 2 MB; group g packs elements [16g,16g+16) from
    // four consecutive uint4 loads.
    const uint4* src =
        (const uint4*)((const int*)mask_raw + (size_t)n * HWSZ);
    for (int it = 0; it < 64; ++it) {
      const int g = t + it * K1_THREADS;
      const uint4 a = src[4 * g + 0];
      const uint4 b = src[4 * g + 1];
      const uint4 c = src[4 * g + 2];
      const uint4 d = src[4 * g + 3];
      sbm16[g] = (unsigned short)(lsb4_i32(a) | (lsb4_i32(b) << 4) |
                                  (lsb4_i32(c) << 8) | (lsb4_i32(d) << 12));
    }
  }
  __syncthreads();

  // Validity eval: wave-aligned chunks so __ballot packs 64 consecutive
  // pairs; 8 waves x 10 iters covers 5120 >= 5000 (tail ballots are 0s).
  const int lane = t & 63;
  const int wv = t >> 6;                 // 0..7
  #pragma unroll
  for (int j = 0; j < 10; ++j) {
    const int il = wv * 64 + lane + j * K1_THREADS;  // pair idx within row
    bool valid = false;
    if (il < SAMPLE_NUM) {
      const int i = n * SAMPLE_NUM + il;
      const int a = idxA[i];
      const int b = idxB[i];
      valid =
          ((sbm[a >> 5] >> (a & 31)) & (sbm[b >> 5] >> (b & 31)) & 1u) != 0u;
    }
    const unsigned long long bal = __ballot(valid);
    if (lane == 0) bitmap[n * (ROW_BITS_PAD / 64) + (wv + j * 8)] = bal;
  }
}

// Kernel 2: per-block partials -> ws[3*blockIdx + {0,1,2}] (plain stores).
// Mask-free: validity from the 20 KB bitmap; only valid lanes gather data.
__global__ void __launch_bounds__(BLOCK)
ranking_loss_partial(const float* __restrict__ pred,
                     const float* __restrict__ targ,
                     const unsigned int* __restrict__ bitmap32,
                     const int* __restrict__ idxA,
                     const int* __restrict__ idxB,
                     float* __restrict__ ws, int total) {
  const float hi = 1.0f + SIGMA_F;
  const float lo = 1.0f / (1.0f + SIGMA_F);

  float eq_sum = 0.0f, uneq_sum = 0.0f, valid = 0.0f;
  const int i = blockIdx.x * BLOCK + threadIdx.x;
  if (i < total) {
    const int n = i / SAMPLE_NUM;  // magic-mul division
    const int il = i - n * SAMPLE_NUM;
    // Independent rounds: bitmap word (broadcast-coalesced) || idx loads.
    const unsigned w = bitmap32[n * (ROW_BITS_PAD / 32) + (il >> 5)];
    const int a = idxA[i];
    const int b = idxB[i];

    if ((w >> (il & 31)) & 1u) {
      const int base = n * HWSZ;  // < 16.8M, fits i32
      const int ia_off = base + a;
      const int ib_off = base + b;
      // The mandatory random traffic: 4 gathers for ~25% of lanes.
      const float tA = targ[ia_off];
      const float tB = targ[ib_off];
      const float iA = pred[ia_off];
      const float iB = pred[ib_off];

      valid = 1.0f;
      const float ratio = tA / (tB + EPS_F);  // targ in [0.1,10] -> safe
      if (ratio < hi && ratio > lo) {
        const float d = iA - iB;
        eq_sum = d * d;  // ALPHA == 1.0
      } else {
        const float label = (ratio >= hi) ? 1.0f : -1.0f;
        const float x = (iB - iA) * label;
        uneq_sum = (x > 20.0f) ? x : log1pf(expf(x));  // log1p(exp(x))
      }
    }
  }

  // Wave-64 shuffle reduction
  #pragma unroll
  for (int off = 32; off > 0; off >>= 1) {
    eq_sum   += __shfl_down(eq_sum, off, 64);
    uneq_sum += __shfl_down(uneq_sum, off, 64);
    valid    += __shfl_down(valid, off, 64);
  }

  __shared__ float s_eq[4], s_un[4], s_va[4];
  const int lane = threadIdx.x & 63;
  const int wave = threadIdx.x >> 6;
  if (lane == 0) {
    s_eq[wave] = eq_sum;
    s_un[wave] = uneq_sum;
    s_va[wave] = valid;
  }
  __syncthreads();

  if (threadIdx.x == 0) {
    float e = 0.0f, u = 0.0f, v = 0.0f;
    #pragma unroll
    for (int w2 = 0; w2 < BLOCK / 64; ++w2) {
      e += s_eq[w2];
      u += s_un[w2];
      v += s_va[w2];
    }
    float* slot = ws + 3 * blockIdx.x;
    slot[0] = e;
    slot[1] = u;
    slot[2] = v;
  }
}

// Kernel 3: single block reduces all per-block slots and writes the scalar.
__global__ void __launch_bounds__(BLOCK)
ranking_loss_finalize(const float* __restrict__ ws, float* __restrict__ out,
                      int nblocks) {
  float e = 0.0f, u = 0.0f, v = 0.0f;
  for (int s = threadIdx.x; s < nblocks; s += BLOCK) {
    e += ws[3 * s + 0];
    u += ws[3 * s + 1];
    v += ws[3 * s + 2];
  }
  #pragma unroll
  for (int off = 32; off > 0; off >>= 1) {
    e += __shfl_down(e, off, 64);
    u += __shfl_down(u, off, 64);
    v += __shfl_down(v, off, 64);
  }
  __shared__ float s_e[4], s_u[4], s_v[4];
  const int lane = threadIdx.x & 63;
  const int wave = threadIdx.x >> 6;
  if (lane == 0) {
    s_e[wave] = e;
    s_u[wave] = u;
    s_v[wave] = v;
  }
  __syncthreads();
  if (threadIdx.x == 0) {
    float te = 0.0f, tu = 0.0f, tv = 0.0f;
    #pragma unroll
    for (int w = 0; w < BLOCK / 64; ++w) {
      te += s_e[w];
      tu += s_u[w];
      tv += s_v[w];
    }
    out[0] = (te + tu) / (tv + EPS_F);  // ALPHA=1, LOSS_WEIGHT=1
  }
}

extern "C" void kernel_launch(void* const* d_in, const int* in_sizes, int n_in,
                              void* d_out, int out_size, void* d_ws,
                              size_t ws_size, hipStream_t stream) {
  const float* pred = (const float*)d_in[0];
  const float* targ = (const float*)d_in[1];
  const void* mask = d_in[2];  // bool array; layout detected on device
  const int* idxA = (const int*)d_in[3];
  const int* idxB = (const int*)d_in[4];
  float* out = (float*)d_out;
  float* ws = (float*)d_ws;

  const int total = in_sizes[3];           // N * SAMPLE_NUM = 160000
  const int rows = total / SAMPLE_NUM;     // 32
  const int grid = (total + BLOCK - 1) / BLOCK;  // 625 blocks

  // ws layout: [0, 7500B) = per-block partials; [8192, 8192+20KB) =
  // validity bitmap (rows x 5120 bits). All rewritten every launch.
  unsigned long long* bm64 =
      (unsigned long long*)((char*)d_ws + BM_OFF_BYTES);
  const unsigned int* bm32 = (const unsigned int*)bm64;

  mask_validity<<<rows, K1_THREADS, HWSZ / 8, stream>>>(mask, idxA, idxB,
                                                        bm64);
  ranking_loss_partial<<<grid, BLOCK, 0, stream>>>(pred, targ, bm32, idxA,
                                                   idxB, ws, total);
  ranking_loss_finalize<<<1, BLOCK, 0, stream>>>(ws, out, grid);
}

// Round 6
// 182.710 us; speedup vs baseline: 1.2042x; 1.2042x over previous
//
#include <hip/hip_runtime.h>
#include <math.h>

// Problem constants (from reference):
//   N=32, C=1, H=512, W=1024 -> HW = 524288 per batch row
//   SAMPLE_NUM = 5000 pairs per row -> 160000 pairs total
//   SIGMA = 0.03, ALPHA = 1.0, EPS = 1e-6, LOSS_WEIGHT = 1.0
#define SAMPLE_NUM 5000
#define HWSZ (512 * 1024)
#define SIGMA_F 0.03f
#define EPS_F 1e-6f
#define BLOCK 256
#define NTOT 32
#define PACK_WORDS16 (NTOT * HWSZ / 16)  // 1,048,576 ushorts (2 MB)
#define ROW_BITS_PAD 5120                // per-row bitmap bits (5000 used)
#define BM_OFF_BYTES 8192                // bitmap at ws+8192 (20 KB)
#define PK_OFF_BYTES 32768               // packed mask at ws+32768 (2 MB)

// R9 design notes:
//  - R8b post-mortem: K1 (monolithic per-row) = 70 us because 32 blocks =
//    32 CUs = 12.5% of machine; coalesced streaming at ~15 GB/s/CU is
//    latency-bound (486 GB/s agg, occupancy 2.6%). K2 with bitmap DID drop
//    ~33 -> ~10 us (below cutoff; residual arithmetic). Keep K2; fix K1.
//  - Split K1: K1a = full-grid pack (R7's verified kernel, 4096 blocks,
//    16 MB coalesced @ machine BW ~ 3-4 us) -> 2 MB packed mask in ws.
//    K1b = per-row validity only: coalesced 64 KB LDS load of packed row
//    (2 MB total) + 10k LDS lookups + ballot -> 20 KB bitmap. ~4 us.
//  - ws layout: [0,7.5K) partials | [8192,+20K) bitmap | [32768,+2M) pack.
//    ws is 256 MiB (the harness poison fill) -> plenty.

// Kernel 1a: bit-pack the bool mask. Each thread packs 16 elements -> ushort.
__global__ void __launch_bounds__(BLOCK)
mask_pack(const void* __restrict__ mask_raw,
          unsigned short* __restrict__ out) {
  // Mask layout detection (thread-uniform). int32 bools: every word is 0/1.
  // Byte bools: uint32 view >1 with P=7/8 per word; 32 words -> P_err=8^-32.
  const unsigned int* mw = (const unsigned int*)mask_raw;
  bool mask_is_i32 = true;
  #pragma unroll
  for (int w = 0; w < 32; ++w) {
    if (mw[w] > 1u) mask_is_i32 = false;
  }

  const int i = blockIdx.x * BLOCK + threadIdx.x;  // 1M threads
  if (i >= PACK_WORDS16) return;

  unsigned short r;
  if (mask_is_i32) {
    const int* m32 = (const int*)mask_raw;
    const int b = i * 16;
    unsigned v = 0;
    #pragma unroll
    for (int k = 0; k < 16; ++k) v |= (unsigned)(m32[b + k] & 1) << k;
    r = (unsigned short)v;
  } else {
    // 16 bool bytes -> 16 bits. ((u & 0x01010101)*0x01020408)>>24 puts the
    // 4 byte-LSBs at bits 0..3. Validated end-to-end in R7 (absmax=0).
    const uint4 v = ((const uint4*)mask_raw)[i];
    const unsigned n0 = ((v.x & 0x01010101u) * 0x01020408u) >> 24;
    const unsigned n1 = ((v.y & 0x01010101u) * 0x01020408u) >> 24;
    const unsigned n2 = ((v.z & 0x01010101u) * 0x01020408u) >> 24;
    const unsigned n3 = ((v.w & 0x01010101u) * 0x01020408u) >> 24;
    r = (unsigned short)((n0 & 0xFu) | ((n1 & 0xFu) << 4) |
                         ((n2 & 0xFu) << 8) | ((n3 & 0xFu) << 12));
  }
  out[i] = r;
}

// Kernel 1b: one block per row. Coalesced-load the packed row (64 KB) into
// LDS, evaluate validity of the row's 5000 pairs, ballot -> bitmap in ws.
__global__ void __launch_bounds__(1024)
mask_validity(const unsigned int* __restrict__ mpack32,
              const int* __restrict__ idxA, const int* __restrict__ idxB,
              unsigned long long* __restrict__ bitmap) {
  extern __shared__ unsigned int sbm[];  // HWSZ/32 = 16384 words = 64 KB
  const int n = blockIdx.x;
  const int t = threadIdx.x;

  // Coalesced 64 KB load: 4096 uint4 = 1024 threads x 4.
  const uint4* src = (const uint4*)(mpack32 + n * (HWSZ / 32));
  uint4* dst = (uint4*)sbm;
  #pragma unroll
  for (int it = 0; it < 4; ++it) {
    dst[t + it * 1024] = src[t + it * 1024];
  }
  __syncthreads();

  // Validity eval: wave-aligned chunks so __ballot packs 64 consecutive
  // pairs; 16 waves x 5 iters covers 5120 >= 5000 (tail ballots are 0s).
  const int lane = t & 63;
  const int wv = t >> 6;  // 0..15
  #pragma unroll
  for (int j = 0; j < 5; ++j) {
    const int il = wv * 64 + lane + j * 1024;  // pair index within row
    bool valid = false;
    if (il < SAMPLE_NUM) {
      const int i = n * SAMPLE_NUM + il;
      const int a = idxA[i];
      const int b = idxB[i];
      valid =
          ((sbm[a >> 5] >> (a & 31)) & (sbm[b >> 5] >> (b & 31)) & 1u) != 0u;
    }
    const unsigned long long bal = __ballot(valid);
    if (lane == 0) bitmap[n * (ROW_BITS_PAD / 64) + (wv + j * 16)] = bal;
  }
}

// Kernel 2: per-block partials -> ws[3*blockIdx + {0,1,2}] (plain stores).
// Mask-free: validity from the 20 KB bitmap; only valid lanes gather data.
__global__ void __launch_bounds__(BLOCK)
ranking_loss_partial(const float* __restrict__ pred,
                     const float* __restrict__ targ,
                     const unsigned int* __restrict__ bitmap32,
                     const int* __restrict__ idxA,
                     const int* __restrict__ idxB,
                     float* __restrict__ ws, int total) {
  const float hi = 1.0f + SIGMA_F;
  const float lo = 1.0f / (1.0f + SIGMA_F);

  float eq_sum = 0.0f, uneq_sum = 0.0f, valid = 0.0f;
  const int i = blockIdx.x * BLOCK + threadIdx.x;
  if (i < total) {
    const int n = i / SAMPLE_NUM;  // magic-mul division
    const int il = i - n * SAMPLE_NUM;
    // Independent rounds: bitmap word (broadcast-coalesced) || idx loads.
    const unsigned w = bitmap32[n * (ROW_BITS_PAD / 32) + (il >> 5)];
    const int a = idxA[i];
    const int b = idxB[i];

    if ((w >> (il & 31)) & 1u) {
      const int base = n * HWSZ;  // < 16.8M, fits i32
      const int ia_off = base + a;
      const int ib_off = base + b;
      // The mandatory random traffic: 4 gathers for ~25% of lanes.
      const float tA = targ[ia_off];
      const float tB = targ[ib_off];
      const float iA = pred[ia_off];
      const float iB = pred[ib_off];

      valid = 1.0f;
      const float ratio = tA / (tB + EPS_F);  // targ in [0.1,10] -> safe
      if (ratio < hi && ratio > lo) {
        const float d = iA - iB;
        eq_sum = d * d;  // ALPHA == 1.0
      } else {
        const float label = (ratio >= hi) ? 1.0f : -1.0f;
        const float x = (iB - iA) * label;
        uneq_sum = (x > 20.0f) ? x : log1pf(expf(x));  // log1p(exp(x))
      }
    }
  }

  // Wave-64 shuffle reduction
  #pragma unroll
  for (int off = 32; off > 0; off >>= 1) {
    eq_sum   += __shfl_down(eq_sum, off, 64);
    uneq_sum += __shfl_down(uneq_sum, off, 64);
    valid    += __shfl_down(valid, off, 64);
  }

  __shared__ float s_eq[4], s_un[4], s_va[4];
  const int lane = threadIdx.x & 63;
  const int wave = threadIdx.x >> 6;
  if (lane == 0) {
    s_eq[wave] = eq_sum;
    s_un[wave] = uneq_sum;
    s_va[wave] = valid;
  }
  __syncthreads();

  if (threadIdx.x == 0) {
    float e = 0.0f, u = 0.0f, v = 0.0f;
    #pragma unroll
    for (int w2 = 0; w2 < BLOCK / 64; ++w2) {
      e += s_eq[w2];
      u += s_un[w2];
      v += s_va[w2];
    }
    float* slot = ws + 3 * blockIdx.x;
    slot[0] = e;
    slot[1] = u;
    slot[2] = v;
  }
}

// Kernel 3: single block reduces all per-block slots and writes the scalar.
__global__ void __launch_bounds__(BLOCK)
ranking_loss_finalize(const float* __restrict__ ws, float* __restrict__ out,
                      int nblocks) {
  float e = 0.0f, u = 0.0f, v = 0.0f;
  for (int s = threadIdx.x; s < nblocks; s += BLOCK) {
    e += ws[3 * s + 0];
    u += ws[3 * s + 1];
    v += ws[3 * s + 2];
  }
  #pragma unroll
  for (int off = 32; off > 0; off >>= 1) {
    e += __shfl_down(e, off, 64);
    u += __shfl_down(u, off, 64);
    v += __shfl_down(v, off, 64);
  }
  __shared__ float s_e[4], s_u[4], s_v[4];
  const int lane = threadIdx.x & 63;
  const int wave = threadIdx.x >> 6;
  if (lane == 0) {
    s_e[wave] = e;
    s_u[wave] = u;
    s_v[wave] = v;
  }
  __syncthreads();
  if (threadIdx.x == 0) {
    float te = 0.0f, tu = 0.0f, tv = 0.0f;
    #pragma unroll
    for (int w = 0; w < BLOCK / 64; ++w) {
      te += s_e[w];
      tu += s_u[w];
      tv += s_v[w];
    }
    out[0] = (te + tu) / (tv + EPS_F);  // ALPHA=1, LOSS_WEIGHT=1
  }
}

extern "C" void kernel_launch(void* const* d_in, const int* in_sizes, int n_in,
                              void* d_out, int out_size, void* d_ws,
                              size_t ws_size, hipStream_t stream) {
  const float* pred = (const float*)d_in[0];
  const float* targ = (const float*)d_in[1];
  const void* mask = d_in[2];  // bool array; layout detected on device
  const int* idxA = (const int*)d_in[3];
  const int* idxB = (const int*)d_in[4];
  float* out = (float*)d_out;
  float* ws = (float*)d_ws;

  const int total = in_sizes[3];           // N * SAMPLE_NUM = 160000
  const int rows = total / SAMPLE_NUM;     // 32
  const int grid = (total + BLOCK - 1) / BLOCK;  // 625 blocks

  unsigned short* mpack16 = (unsigned short*)((char*)d_ws + PK_OFF_BYTES);
  const unsigned int* mpack32 = (const unsigned int*)mpack16;
  unsigned long long* bm64 =
      (unsigned long long*)((char*)d_ws + BM_OFF_BYTES);
  const unsigned int* bm32 = (const unsigned int*)bm64;

  mask_pack<<<PACK_WORDS16 / BLOCK, BLOCK, 0, stream>>>(mask, mpack16);
  mask_validity<<<rows, 1024, HWSZ / 8, stream>>>(mpack32, idxA, idxB, bm64);
  ranking_loss_partial<<<grid, BLOCK, 0, stream>>>(pred, targ, bm32, idxA,
                                                   idxB, ws, total);
  ranking_loss_finalize<<<1, BLOCK, 0, stream>>>(ws, out, grid);
}